// Round 3
// baseline (755.418 us; speedup 1.0000x reference)
//
#include <hip/hip_runtime.h>
#include <math.h>

#define INV_SQRT2f 0.70710678118654752440f
#define SILU_SCALEf (1.0f / 0.6f)

typedef __attribute__((ext_vector_type(8))) short bf16x8;
typedef __attribute__((ext_vector_type(4))) short bf16x4;
typedef __attribute__((ext_vector_type(4))) float f32x4;

__device__ __forceinline__ float ssilu(float v) {
    return (v / (1.0f + __expf(-v))) * SILU_SCALEf;
}

__device__ __forceinline__ unsigned short f2bf(float f) {
    unsigned int u = __float_as_uint(f);
    unsigned int r = (u + 0x7FFFu + ((u >> 16) & 1u)) >> 16;
    return (unsigned short)r;
}

// ---------------------------------------------------------------------------
// Edge phase: counting-sort by atom (CSR) — unchanged from measured-good R3.
// ---------------------------------------------------------------------------
__global__ void zero_kernel(int* __restrict__ p, int n)
{
    int i = blockIdx.x * blockDim.x + threadIdx.x;
    for (; i < n; i += gridDim.x * blockDim.x) p[i] = 0;
}

__global__ void hist_kernel(const int* __restrict__ id_j, int* __restrict__ counts,
                            int nEdges)
{
    int i = blockIdx.x * blockDim.x + threadIdx.x;
    for (; i < nEdges; i += gridDim.x * blockDim.x)
        atomicAdd(&counts[id_j[i]], 1);
}

__global__ void scan_reduce(const int* __restrict__ counts, int* __restrict__ bsum,
                            int n)
{
    __shared__ int s[256];
    int base = blockIdx.x * 1024;
    int t = threadIdx.x;
    int v = 0;
#pragma unroll
    for (int k = 0; k < 4; ++k) {
        int i = base + t + k * 256;
        if (i < n) v += counts[i];
    }
    s[t] = v;
    __syncthreads();
    for (int off = 128; off > 0; off >>= 1) {
        if (t < off) s[t] += s[t + off];
        __syncthreads();
    }
    if (t == 0) bsum[blockIdx.x] = s[0];
}

// wave-parallel exclusive scan of chunk totals (single 64-thread block)
__global__ void scan_sums(int* __restrict__ bsum, int nb)
{
    int l = threadIdx.x & 63;
    int carry = 0;
    for (int base = 0; base < nb; base += 64) {
        int idx = base + l;
        int orig = (idx < nb) ? bsum[idx] : 0;
        int v = orig;
#pragma unroll
        for (int off = 1; off < 64; off <<= 1) {
            int u = __shfl_up(v, off, 64);
            if (l >= off) v += u;
        }
        if (idx < nb) bsum[idx] = carry + v - orig;
        carry += __shfl(v, 63, 64);
    }
}

__global__ void scan_write(const int* __restrict__ counts, const int* __restrict__ bsum,
                           int* __restrict__ offsets, int* __restrict__ cursor, int n)
{
    __shared__ int s[256];
    int base = blockIdx.x * 1024;
    int t = threadIdx.x;
    int v[4];
    int tot = 0;
#pragma unroll
    for (int k = 0; k < 4; ++k) {
        int i = base + t * 4 + k;
        int c = (i < n) ? counts[i] : 0;
        v[k] = tot; tot += c;
    }
    s[t] = tot;
    __syncthreads();
    for (int off = 1; off < 256; off <<= 1) {
        int x = (t >= off) ? s[t - off] : 0;
        __syncthreads();
        s[t] += x;
        __syncthreads();
    }
    int excl = (t > 0) ? s[t - 1] : 0;
    int bo = bsum[blockIdx.x];
#pragma unroll
    for (int k = 0; k < 4; ++k) {
        int i = base + t * 4 + k;
        if (i < n) { int o = bo + excl + v[k]; offsets[i] = o; cursor[i] = o; }
    }
}

__global__ void order_kernel(const int* __restrict__ id_j, int* __restrict__ cursor,
                             int* __restrict__ order, int nEdges)
{
    int i = blockIdx.x * blockDim.x + threadIdx.x;
    for (; i < nEdges; i += gridDim.x * blockDim.x) {
        int j = id_j[i];
        int p = atomicAdd(&cursor[j], 1);
        order[p] = i;
    }
}

// ---------------------------------------------------------------------------
// Weight conversion: f32 [256][256] row-major -> bf16 fragment-ordered blob.
// blob halfword idx = ((L*8 + c)*1024 + g*256 + n)*8 + j ; element W_L[k][n],
// k = c*32 + g*8 + j.  One block per (L,c); coalesced reads via LDS transpose.
// ---------------------------------------------------------------------------
__global__ void __launch_bounds__(256) wconv_kernel(
    const float* __restrict__ W1, const float* __restrict__ res_W,
    unsigned short* __restrict__ blob)
{
    __shared__ float ws[32][260];
    const int b = blockIdx.x;        // b = L*8 + c
    const int L = b >> 3, c = b & 7;
    const int t = threadIdx.x;
    const float* W = (L == 0) ? W1 : res_W + (size_t)(L - 1) * 65536;

#pragma unroll
    for (int r = 0; r < 32; ++r)
        ws[r][t] = W[(size_t)(c * 32 + r) * 256 + t];
    __syncthreads();

    unsigned short* dst = blob + (size_t)b * 8192;
#pragma unroll
    for (int q = 0; q < 32; ++q) {
        int flat = q * 256 + t;
        int jj = flat & 7, n = (flat >> 3) & 255, g = flat >> 11;
        dst[flat] = f2bf(ws[g * 8 + jj][n]);
    }
}

// ---------------------------------------------------------------------------
// Gather, wave-per-atom: block = 4 waves = 4 atoms. Lane l owns columns
// 4l..4l+3 (f32x4 accumulator). Per edge: ONE global_load_dwordx4 covers the
// whole 1 KB m-row per wave (64 lanes x 16 B, perfectly coalesced) -> 4x the
// in-flight bytes per wave of the old thread-per-column layout; rbf row and
// edge indices are issued once per atom (not once per wave-quarter).
// Output written bf16 in the dense kernel's swizzled LDS image layout:
//   halfword idx = tile*16384 + ((r*256 + col) ^ ((r&7)<<3)), tile=j>>6, r=j&63.
// ---------------------------------------------------------------------------
__global__ void __launch_bounds__(256) gather_kernel(
    const float* __restrict__ m, const float* __restrict__ rbf,
    const int* __restrict__ order, const int* __restrict__ offsets,
    const int* __restrict__ counts, const float* __restrict__ W_rbf,
    unsigned short* __restrict__ x2b)
{
    const int lane = threadIdx.x & 63;
    const int wv   = threadIdx.x >> 6;              // 0..3
    const int j    = blockIdx.x * 4 + wv;           // atom
    if (j >= 50000 + 48) return;                    // (generous guard; grid exact)

    // weights for this lane's 4 columns: w[k] = W_rbf[k][4*lane .. 4*lane+3]
    f32x4 w[16];
#pragma unroll
    for (int k = 0; k < 16; ++k)
        w[k] = *reinterpret_cast<const f32x4*>(W_rbf + k * 256 + 4 * lane);

    const int s = offsets[j];
    const int n = counts[j];

    f32x4 acc = (f32x4){0.0f, 0.0f, 0.0f, 0.0f};
    int i = 0;
    for (; i + 1 < n; i += 2) {
        int e0 = order[s + i], e1 = order[s + i + 1];
        f32x4 mv0 = *reinterpret_cast<const f32x4*>(m + (long long)e0 * 256 + 4 * lane);
        f32x4 mv1 = *reinterpret_cast<const f32x4*>(m + (long long)e1 * 256 + 4 * lane);
        const float4* rp0 = reinterpret_cast<const float4*>(rbf + (long long)e0 * 16);
        const float4* rp1 = reinterpret_cast<const float4*>(rbf + (long long)e1 * 16);
        float4 ra0 = rp0[0], rb0 = rp0[1], rc0 = rp0[2], rd0 = rp0[3];
        float4 ra1 = rp1[0], rb1 = rp1[1], rc1 = rp1[2], rd1 = rp1[3];
        f32x4 g0 = w[0] * ra0.x + w[1] * ra0.y + w[2] * ra0.z + w[3] * ra0.w
                 + w[4] * rb0.x + w[5] * rb0.y + w[6] * rb0.z + w[7] * rb0.w
                 + w[8] * rc0.x + w[9] * rc0.y + w[10] * rc0.z + w[11] * rc0.w
                 + w[12] * rd0.x + w[13] * rd0.y + w[14] * rd0.z + w[15] * rd0.w;
        f32x4 g1 = w[0] * ra1.x + w[1] * ra1.y + w[2] * ra1.z + w[3] * ra1.w
                 + w[4] * rb1.x + w[5] * rb1.y + w[6] * rb1.z + w[7] * rb1.w
                 + w[8] * rc1.x + w[9] * rc1.y + w[10] * rc1.z + w[11] * rc1.w
                 + w[12] * rd1.x + w[13] * rd1.y + w[14] * rd1.z + w[15] * rd1.w;
        acc += mv0 * g0 + mv1 * g1;
    }
    if (i < n) {
        int e0 = order[s + i];
        f32x4 mv0 = *reinterpret_cast<const f32x4*>(m + (long long)e0 * 256 + 4 * lane);
        const float4* rp0 = reinterpret_cast<const float4*>(rbf + (long long)e0 * 16);
        float4 ra0 = rp0[0], rb0 = rp0[1], rc0 = rp0[2], rd0 = rp0[3];
        f32x4 g0 = w[0] * ra0.x + w[1] * ra0.y + w[2] * ra0.z + w[3] * ra0.w
                 + w[4] * rb0.x + w[5] * rb0.y + w[6] * rb0.z + w[7] * rb0.w
                 + w[8] * rc0.x + w[9] * rc0.y + w[10] * rc0.z + w[11] * rc0.w
                 + w[12] * rd0.x + w[13] * rd0.y + w[14] * rd0.z + w[15] * rd0.w;
        acc += mv0 * g0;
    }

    const int tile = j >> 6, r = j & 63;
    const int idx = (r * 256 + 4 * lane) ^ ((r & 7) << 3);
    bf16x4 o = {(short)f2bf(acc[0]), (short)f2bf(acc[1]),
                (short)f2bf(acc[2]), (short)f2bf(acc[3])};
    *reinterpret_cast<bf16x4*>(x2b + (size_t)tile * 16384 + idx) = o;
}

// ---------------------------------------------------------------------------
// Dense chain, 8-wave variant (measured-good structure). Load phase is a pure
// global->LDS DMA: x2b is already bf16 in the exact swizzled LDS image.
// ---------------------------------------------------------------------------
__global__ void __launch_bounds__(512) dense_kernel(
    const unsigned short* __restrict__ x2b, const unsigned short* __restrict__ blob,
    const float* __restrict__ scale, float* __restrict__ out, int nAtoms)
{
    __shared__ __align__(16) unsigned short xs[64 * 256];  // swizzled: idx ^= (row&7)<<3

    const int tid = threadIdx.x;
    const int lane = tid & 63;
    const int w = tid >> 6;          // 0..7
    const int l15 = lane & 15;
    const int g = lane >> 4;
    const long long blockRow = (long long)blockIdx.x * 64;

    // DMA the 32 KB slab: LDS dest = wave-uniform base + lane*16 (linear),
    // global source = identical byte offset (x2b stores the LDS image).
    {
        const char* gsrc = (const char*)(x2b + (size_t)blockIdx.x * 16384) + (size_t)tid * 16;
        char* lbase = (char*)xs + w * 1024;   // wave-uniform
#pragma unroll
        for (int i = 0; i < 4; ++i) {
            __builtin_amdgcn_global_load_lds(
                (const __attribute__((address_space(1))) unsigned int*)(gsrc + i * 8192),
                (__attribute__((address_space(3))) unsigned int*)(lbase + i * 8192),
                16, 0, 0);
        }
        asm volatile("s_waitcnt vmcnt(0)" ::: "memory");
    }

    const float sc = scale[0];
    f32x4 acc[4][2];
    float xrun[4][2][4];

    for (int L = 0; L < 7; ++L) {
        __syncthreads();             // L=0: fences the DMA for all waves

#pragma unroll
        for (int mt = 0; mt < 4; ++mt)
#pragma unroll
            for (int ct = 0; ct < 2; ++ct) acc[mt][ct] = (f32x4){0, 0, 0, 0};

        const unsigned short* wlayer = blob + (size_t)L * 65536;

        for (int c = 0; c < 8; ++c) {
            bf16x8 af[4], bfr[2];
#pragma unroll
            for (int mt = 0; mt < 4; ++mt) {
                int arow = mt * 16 + l15;
                int idx = (arow * 256 + c * 32 + g * 8) ^ ((arow & 7) << 3);
                af[mt] = *reinterpret_cast<const bf16x8*>(&xs[idx]);
            }
#pragma unroll
            for (int ct = 0; ct < 2; ++ct) {
                int n = w * 32 + ct * 16 + l15;
                bfr[ct] = *reinterpret_cast<const bf16x8*>(wlayer + ((size_t)c * 1024 + g * 256 + n) * 8);
            }
#pragma unroll
            for (int mt = 0; mt < 4; ++mt)
#pragma unroll
                for (int ct = 0; ct < 2; ++ct)
                    acc[mt][ct] = __builtin_amdgcn_mfma_f32_16x16x32_bf16(
                        af[mt], bfr[ct], acc[mt][ct], 0, 0, 0);
        }

        __syncthreads();

        if (L == 0) {
#pragma unroll
            for (int mt = 0; mt < 4; ++mt)
#pragma unroll
                for (int ct = 0; ct < 2; ++ct)
#pragma unroll
                    for (int r = 0; r < 4; ++r)
                        xrun[mt][ct][r] = ssilu(acc[mt][ct][r] * sc);
        } else if (L == 1 || L == 3 || L == 5) {
#pragma unroll
            for (int mt = 0; mt < 4; ++mt)
#pragma unroll
                for (int ct = 0; ct < 2; ++ct)
#pragma unroll
                    for (int r = 0; r < 4; ++r) {
                        float v = ssilu(acc[mt][ct][r]);
                        int row = mt * 16 + g * 4 + r;
                        int col = w * 32 + ct * 16 + l15;
                        xs[(row * 256 + col) ^ ((row & 7) << 3)] = f2bf(v);
                    }
            continue;
        } else {
#pragma unroll
            for (int mt = 0; mt < 4; ++mt)
#pragma unroll
                for (int ct = 0; ct < 2; ++ct)
#pragma unroll
                    for (int r = 0; r < 4; ++r)
                        xrun[mt][ct][r] = (xrun[mt][ct][r] + ssilu(acc[mt][ct][r])) * INV_SQRT2f;
        }

        if (L < 6) {
#pragma unroll
            for (int mt = 0; mt < 4; ++mt)
#pragma unroll
                for (int ct = 0; ct < 2; ++ct)
#pragma unroll
                    for (int r = 0; r < 4; ++r) {
                        int row = mt * 16 + g * 4 + r;
                        int col = w * 32 + ct * 16 + l15;
                        xs[(row * 256 + col) ^ ((row & 7) << 3)] = f2bf(xrun[mt][ct][r]);
                    }
        } else {
#pragma unroll
            for (int mt = 0; mt < 4; ++mt) {
#pragma unroll
                for (int r = 0; r < 4; ++r) {
                    long long grow = blockRow + mt * 16 + g * 4 + r;
                    if (grow < nAtoms) {
#pragma unroll
                        for (int ct = 0; ct < 2; ++ct)
                            out[grow * 256 + w * 32 + ct * 16 + l15] = xrun[mt][ct][r];
                    }
                }
            }
        }
    }
}

// ---------------------------------------------------------------------------
extern "C" void kernel_launch(void* const* d_in, const int* in_sizes, int n_in,
                              void* d_out, int out_size, void* d_ws, size_t ws_size,
                              hipStream_t stream)
{
    const float* m     = (const float*)d_in[1];
    const float* rbf   = (const float*)d_in[2];
    const int*   id_j  = (const int*)d_in[3];
    const float* W_rbf = (const float*)d_in[4];
    const float* W1    = (const float*)d_in[5];
    const float* res_W = (const float*)d_in[6];
    const float* scale = (const float*)d_in[7];

    const int nAtoms = in_sizes[0] / 256;   // 50000
    const int nEdges = in_sizes[1] / 256;   // 1000000

    float* out = (float*)d_out;

    const int nTiles = (nAtoms + 63) / 64;  // 782

    // ws layout (bytes):
    //   [0, 25624576)            x2b: bf16 swizzled tiles [782][64*256]
    //   [25690112, 26607616)     blob: bf16 7*65536
    //   [26738688, ...)          int scratch
    unsigned short* x2b  = (unsigned short*)d_ws;
    unsigned short* blob = (unsigned short*)((char*)d_ws + 25690112);
    int* ibase   = (int*)((char*)d_ws + 26738688);
    int* counts  = ibase;                 // 65536
    int* offsets = ibase + 65536;         // 65536
    int* cursor  = ibase + 131072;        // 65536
    int* bsum    = ibase + 196608;        // 1024
    int* order   = ibase + 197632;        // nEdges

    zero_kernel<<<64, 256, 0, stream>>>(counts, 65536);

    wconv_kernel<<<56, 256, 0, stream>>>(W1, res_W, blob);

    hist_kernel<<<2048, 256, 0, stream>>>(id_j, counts, nEdges);
    int nb = (nAtoms + 1023) / 1024;
    scan_reduce<<<nb, 256, 0, stream>>>(counts, bsum, nAtoms);
    scan_sums<<<1, 64, 0, stream>>>(bsum, nb);
    scan_write<<<nb, 256, 0, stream>>>(counts, bsum, offsets, cursor, nAtoms);
    order_kernel<<<2048, 256, 0, stream>>>(id_j, cursor, order, nEdges);

    gather_kernel<<<(nAtoms + 3) / 4, 256, 0, stream>>>(m, rbf, order, offsets,
                                                        counts, W_rbf, x2b);

    dense_kernel<<<nTiles, 512, 0, stream>>>(x2b, blob, scale, out, nAtoms);
}

// Round 4
// 546.887 us; speedup vs baseline: 1.3813x; 1.3813x over previous
//
#include <hip/hip_runtime.h>
#include <math.h>

#define INV_SQRT2f 0.70710678118654752440f
#define SILU_SCALEf (1.0f / 0.6f)

typedef __attribute__((ext_vector_type(8))) short bf16x8;
typedef __attribute__((ext_vector_type(4))) float f32x4;

__device__ __forceinline__ float ssilu(float v) {
    return (v / (1.0f + __expf(-v))) * SILU_SCALEf;
}

__device__ __forceinline__ unsigned short f2bf(float f) {
    unsigned int u = __float_as_uint(f);
    unsigned int r = (u + 0x7FFFu + ((u >> 16) & 1u)) >> 16;
    return (unsigned short)r;
}

// ---------------------------------------------------------------------------
// Edge phase: counting-sort by atom (CSR) — unchanged (measured-good).
// ---------------------------------------------------------------------------
__global__ void zero_kernel(int* __restrict__ p, int n)
{
    int i = blockIdx.x * blockDim.x + threadIdx.x;
    for (; i < n; i += gridDim.x * blockDim.x) p[i] = 0;
}

__global__ void hist_kernel(const int* __restrict__ id_j, int* __restrict__ counts,
                            int nEdges)
{
    int i = blockIdx.x * blockDim.x + threadIdx.x;
    for (; i < nEdges; i += gridDim.x * blockDim.x)
        atomicAdd(&counts[id_j[i]], 1);
}

__global__ void scan_reduce(const int* __restrict__ counts, int* __restrict__ bsum,
                            int n)
{
    __shared__ int s[256];
    int base = blockIdx.x * 1024;
    int t = threadIdx.x;
    int v = 0;
#pragma unroll
    for (int k = 0; k < 4; ++k) {
        int i = base + t + k * 256;
        if (i < n) v += counts[i];
    }
    s[t] = v;
    __syncthreads();
    for (int off = 128; off > 0; off >>= 1) {
        if (t < off) s[t] += s[t + off];
        __syncthreads();
    }
    if (t == 0) bsum[blockIdx.x] = s[0];
}

// wave-parallel exclusive scan of chunk totals (single 64-thread block)
__global__ void scan_sums(int* __restrict__ bsum, int nb)
{
    int l = threadIdx.x & 63;
    int carry = 0;
    for (int base = 0; base < nb; base += 64) {
        int idx = base + l;
        int orig = (idx < nb) ? bsum[idx] : 0;
        int v = orig;
#pragma unroll
        for (int off = 1; off < 64; off <<= 1) {
            int u = __shfl_up(v, off, 64);
            if (l >= off) v += u;
        }
        if (idx < nb) bsum[idx] = carry + v - orig;
        carry += __shfl(v, 63, 64);
    }
}

__global__ void scan_write(const int* __restrict__ counts, const int* __restrict__ bsum,
                           int* __restrict__ offsets, int* __restrict__ cursor, int n)
{
    __shared__ int s[256];
    int base = blockIdx.x * 1024;
    int t = threadIdx.x;
    int v[4];
    int tot = 0;
#pragma unroll
    for (int k = 0; k < 4; ++k) {
        int i = base + t * 4 + k;
        int c = (i < n) ? counts[i] : 0;
        v[k] = tot; tot += c;
    }
    s[t] = tot;
    __syncthreads();
    for (int off = 1; off < 256; off <<= 1) {
        int x = (t >= off) ? s[t - off] : 0;
        __syncthreads();
        s[t] += x;
        __syncthreads();
    }
    int excl = (t > 0) ? s[t - 1] : 0;
    int bo = bsum[blockIdx.x];
#pragma unroll
    for (int k = 0; k < 4; ++k) {
        int i = base + t * 4 + k;
        if (i < n) { int o = bo + excl + v[k]; offsets[i] = o; cursor[i] = o; }
    }
}

__global__ void order_kernel(const int* __restrict__ id_j, int* __restrict__ cursor,
                             int* __restrict__ order, int nEdges)
{
    int i = blockIdx.x * blockDim.x + threadIdx.x;
    for (; i < nEdges; i += gridDim.x * blockDim.x) {
        int j = id_j[i];
        int p = atomicAdd(&cursor[j], 1);
        order[p] = i;
    }
}

// ---------------------------------------------------------------------------
// Weight conversion: f32 [256][256] row-major -> bf16 fragment-ordered blob.
// ---------------------------------------------------------------------------
__global__ void __launch_bounds__(256) wconv_kernel(
    const float* __restrict__ W1, const float* __restrict__ res_W,
    unsigned short* __restrict__ blob)
{
    __shared__ float ws[32][260];
    const int b = blockIdx.x;        // b = L*8 + c
    const int L = b >> 3, c = b & 7;
    const int t = threadIdx.x;
    const float* W = (L == 0) ? W1 : res_W + (size_t)(L - 1) * 65536;

#pragma unroll
    for (int r = 0; r < 32; ++r)
        ws[r][t] = W[(size_t)(c * 32 + r) * 256 + t];
    __syncthreads();

    unsigned short* dst = blob + (size_t)b * 8192;
#pragma unroll
    for (int q = 0; q < 32; ++q) {
        int flat = q * 256 + t;
        int jj = flat & 7, n = (flat >> 3) & 255, g = flat >> 11;
        dst[flat] = f2bf(ws[g * 8 + jj][n]);
    }
}

// ---------------------------------------------------------------------------
// Gather v4: block-per-atom (proven TLP), DMA-staged edges.
// Per chunk of 16 edges: wave w issues 4 global_load_lds m-row DMAs (1 KB each,
// zero VGPR cost) + 1 rbf DMA (width 4, per-lane src covers 4 edges x 16 f32).
// Explicit vmcnt + RAW s_barrier (no __syncthreads drain in steady loop).
// ~16 KB outstanding per block during stage; ~6 blocks/CU -> ~50-70 KB/CU in
// flight, which the latency model says is what ~6 TB/s needs.
// Consume: thread t owns column t; m read stride-1 (2-way, free), rbf broadcast.
// ---------------------------------------------------------------------------
__global__ void __launch_bounds__(256, 6) gather_kernel(
    const float* __restrict__ m, const float* __restrict__ rbf,
    const int* __restrict__ order, const int* __restrict__ offsets,
    const int* __restrict__ counts, const float* __restrict__ W_rbf,
    unsigned short* __restrict__ x2b)
{
    __shared__ __align__(16) float mbuf[16][256];   // 16 KB
    __shared__ __align__(16) float rbuf[16][16];    // 1 KB
    __shared__ int ord[128];

    const int j = blockIdx.x;
    const int t = threadIdx.x;
    const int lane = t & 63;
    const int w = t >> 6;

    float w16[16];
#pragma unroll
    for (int k = 0; k < 16; ++k) w16[k] = W_rbf[k * 256 + t];

    const int s = offsets[j];
    const int n = counts[j];
    float acc = 0.0f;

    for (int base = 0; base < n; base += 128) {
        const int nn = (n - base < 128) ? (n - base) : 128;
        if (t < 128) ord[t] = order[s + base + ((t < nn) ? t : 0)];
        __syncthreads();

        for (int c0 = 0; c0 < nn; c0 += 16) {
            const int cnt = (nn - c0 < 16) ? (nn - c0) : 16;

            // ---- stage (wave w owns subs w*4 .. w*4+3; pad subs re-fetch edge 0
            //      of the chunk, harmless and L2-hot) ----
#pragma unroll
            for (int q = 0; q < 4; ++q) {
                const int sub = w * 4 + q;
                const int e = ord[c0 + ((sub < cnt) ? sub : 0)];
                const float* src = m + (size_t)e * 256 + lane * 4;
                __builtin_amdgcn_global_load_lds(
                    (const __attribute__((address_space(1))) unsigned int*)src,
                    (__attribute__((address_space(3))) unsigned int*)&mbuf[sub][0],
                    16, 0, 0);
            }
            {
                const int sub = w * 4 + (lane >> 4);
                const int e = ord[c0 + ((sub < cnt) ? sub : 0)];
                const float* src = rbf + (size_t)e * 16 + (lane & 15);
                __builtin_amdgcn_global_load_lds(
                    (const __attribute__((address_space(1))) unsigned int*)src,
                    (__attribute__((address_space(3))) unsigned int*)&rbuf[w * 4][0],
                    4, 0, 0);
            }

            asm volatile("s_waitcnt vmcnt(0)" ::: "memory");
            __builtin_amdgcn_s_barrier();
            asm volatile("" ::: "memory");

            // ---- consume ----
            for (int i = 0; i < cnt; ++i) {
                float mv = mbuf[i][t];
                const float4* rp = reinterpret_cast<const float4*>(&rbuf[i][0]);
                float4 a = rp[0], b = rp[1], cc = rp[2], d = rp[3];
                float g = a.x*w16[0] + a.y*w16[1] + a.z*w16[2] + a.w*w16[3]
                        + b.x*w16[4] + b.y*w16[5] + b.z*w16[6] + b.w*w16[7]
                        + cc.x*w16[8] + cc.y*w16[9] + cc.z*w16[10] + cc.w*w16[11]
                        + d.x*w16[12] + d.y*w16[13] + d.z*w16[14] + d.w*w16[15];
                acc += mv * g;
            }

            asm volatile("" ::: "memory");
            __builtin_amdgcn_s_barrier();
            asm volatile("" ::: "memory");
        }
    }

    const int tile = j >> 6, r = j & 63;
    x2b[(size_t)tile * 16384 + ((r * 256 + t) ^ ((r & 7) << 3))] = f2bf(acc);
}

// ---------------------------------------------------------------------------
// Dense chain, 8-wave variant (measured-good). Pure global->LDS DMA load of
// the pre-swizzled bf16 x2b image, then 7-layer MFMA chain.
// ---------------------------------------------------------------------------
__global__ void __launch_bounds__(512) dense_kernel(
    const unsigned short* __restrict__ x2b, const unsigned short* __restrict__ blob,
    const float* __restrict__ scale, float* __restrict__ out, int nAtoms)
{
    __shared__ __align__(16) unsigned short xs[64 * 256];  // swizzled: idx ^= (row&7)<<3

    const int tid = threadIdx.x;
    const int lane = tid & 63;
    const int w = tid >> 6;          // 0..7
    const int l15 = lane & 15;
    const int g = lane >> 4;
    const long long blockRow = (long long)blockIdx.x * 64;

    {
        const char* gsrc = (const char*)(x2b + (size_t)blockIdx.x * 16384) + (size_t)tid * 16;
        char* lbase = (char*)xs + w * 1024;   // wave-uniform
#pragma unroll
        for (int i = 0; i < 4; ++i) {
            __builtin_amdgcn_global_load_lds(
                (const __attribute__((address_space(1))) unsigned int*)(gsrc + i * 8192),
                (__attribute__((address_space(3))) unsigned int*)(lbase + i * 8192),
                16, 0, 0);
        }
        asm volatile("s_waitcnt vmcnt(0)" ::: "memory");
    }

    const float sc = scale[0];
    f32x4 acc[4][2];
    float xrun[4][2][4];

    for (int L = 0; L < 7; ++L) {
        __syncthreads();             // L=0: fences the DMA for all waves

#pragma unroll
        for (int mt = 0; mt < 4; ++mt)
#pragma unroll
            for (int ct = 0; ct < 2; ++ct) acc[mt][ct] = (f32x4){0, 0, 0, 0};

        const unsigned short* wlayer = blob + (size_t)L * 65536;

        for (int c = 0; c < 8; ++c) {
            bf16x8 af[4], bfr[2];
#pragma unroll
            for (int mt = 0; mt < 4; ++mt) {
                int arow = mt * 16 + l15;
                int idx = (arow * 256 + c * 32 + g * 8) ^ ((arow & 7) << 3);
                af[mt] = *reinterpret_cast<const bf16x8*>(&xs[idx]);
            }
#pragma unroll
            for (int ct = 0; ct < 2; ++ct) {
                int n = w * 32 + ct * 16 + l15;
                bfr[ct] = *reinterpret_cast<const bf16x8*>(wlayer + ((size_t)c * 1024 + g * 256 + n) * 8);
            }
#pragma unroll
            for (int mt = 0; mt < 4; ++mt)
#pragma unroll
                for (int ct = 0; ct < 2; ++ct)
                    acc[mt][ct] = __builtin_amdgcn_mfma_f32_16x16x32_bf16(
                        af[mt], bfr[ct], acc[mt][ct], 0, 0, 0);
        }

        __syncthreads();

        if (L == 0) {
#pragma unroll
            for (int mt = 0; mt < 4; ++mt)
#pragma unroll
                for (int ct = 0; ct < 2; ++ct)
#pragma unroll
                    for (int r = 0; r < 4; ++r)
                        xrun[mt][ct][r] = ssilu(acc[mt][ct][r] * sc);
        } else if (L == 1 || L == 3 || L == 5) {
#pragma unroll
            for (int mt = 0; mt < 4; ++mt)
#pragma unroll
                for (int ct = 0; ct < 2; ++ct)
#pragma unroll
                    for (int r = 0; r < 4; ++r) {
                        float v = ssilu(acc[mt][ct][r]);
                        int row = mt * 16 + g * 4 + r;
                        int col = w * 32 + ct * 16 + l15;
                        xs[(row * 256 + col) ^ ((row & 7) << 3)] = f2bf(v);
                    }
            continue;
        } else {
#pragma unroll
            for (int mt = 0; mt < 4; ++mt)
#pragma unroll
                for (int ct = 0; ct < 2; ++ct)
#pragma unroll
                    for (int r = 0; r < 4; ++r)
                        xrun[mt][ct][r] = (xrun[mt][ct][r] + ssilu(acc[mt][ct][r])) * INV_SQRT2f;
        }

        if (L < 6) {
#pragma unroll
            for (int mt = 0; mt < 4; ++mt)
#pragma unroll
                for (int ct = 0; ct < 2; ++ct)
#pragma unroll
                    for (int r = 0; r < 4; ++r) {
                        int row = mt * 16 + g * 4 + r;
                        int col = w * 32 + ct * 16 + l15;
                        xs[(row * 256 + col) ^ ((row & 7) << 3)] = f2bf(xrun[mt][ct][r]);
                    }
        } else {
#pragma unroll
            for (int mt = 0; mt < 4; ++mt) {
#pragma unroll
                for (int r = 0; r < 4; ++r) {
                    long long grow = blockRow + mt * 16 + g * 4 + r;
                    if (grow < nAtoms) {
#pragma unroll
                        for (int ct = 0; ct < 2; ++ct)
                            out[grow * 256 + w * 32 + ct * 16 + l15] = xrun[mt][ct][r];
                    }
                }
            }
        }
    }
}

// ---------------------------------------------------------------------------
extern "C" void kernel_launch(void* const* d_in, const int* in_sizes, int n_in,
                              void* d_out, int out_size, void* d_ws, size_t ws_size,
                              hipStream_t stream)
{
    const float* m     = (const float*)d_in[1];
    const float* rbf   = (const float*)d_in[2];
    const int*   id_j  = (const int*)d_in[3];
    const float* W_rbf = (const float*)d_in[4];
    const float* W1    = (const float*)d_in[5];
    const float* res_W = (const float*)d_in[6];
    const float* scale = (const float*)d_in[7];

    const int nAtoms = in_sizes[0] / 256;   // 50000
    const int nEdges = in_sizes[1] / 256;   // 1000000

    float* out = (float*)d_out;

    const int nTiles = (nAtoms + 63) / 64;  // 782

    // ws layout (bytes):
    //   [0, 25624576)            x2b: bf16 swizzled tiles [782][64*256]
    //   [25690112, 26607616)     blob: bf16 7*65536
    //   [26738688, ...)          int scratch
    unsigned short* x2b  = (unsigned short*)d_ws;
    unsigned short* blob = (unsigned short*)((char*)d_ws + 25690112);
    int* ibase   = (int*)((char*)d_ws + 26738688);
    int* counts  = ibase;                 // 65536
    int* offsets = ibase + 65536;         // 65536
    int* cursor  = ibase + 131072;        // 65536
    int* bsum    = ibase + 196608;        // 1024
    int* order   = ibase + 197632;        // nEdges

    zero_kernel<<<64, 256, 0, stream>>>(counts, 65536);

    wconv_kernel<<<56, 256, 0, stream>>>(W1, res_W, blob);

    hist_kernel<<<2048, 256, 0, stream>>>(id_j, counts, nEdges);
    int nb = (nAtoms + 1023) / 1024;
    scan_reduce<<<nb, 256, 0, stream>>>(counts, bsum, nAtoms);
    scan_sums<<<1, 64, 0, stream>>>(bsum, nb);
    scan_write<<<nb, 256, 0, stream>>>(counts, bsum, offsets, cursor, nAtoms);
    order_kernel<<<2048, 256, 0, stream>>>(id_j, cursor, order, nEdges);

    gather_kernel<<<nAtoms, 256, 0, stream>>>(m, rbf, order, offsets, counts,
                                              W_rbf, x2b);

    dense_kernel<<<nTiles, 512, 0, stream>>>(x2b, blob, scale, out, nAtoms);
}